// Round 14
// baseline (191.504 us; speedup 1.0000x reference)
//
#include <hip/hip_runtime.h>
#include <hip/hip_bf16.h>

typedef unsigned short u16;
typedef __attribute__((ext_vector_type(4))) float f32x4;
typedef __attribute__((ext_vector_type(8))) short s16x8;  // 8 x bf16 (4 VGPRs)
typedef __attribute__((ext_vector_type(4))) short s16x4;

#define DEVFN static __device__ __forceinline__

DEVFN u16 f2bf(float f) {  // fp32 -> bf16, round-nearest-even
  unsigned u = __float_as_uint(f);
  return (u16)((u + 0x7fffu + ((u >> 16) & 1u)) >> 16);
}
DEVFN float bf2f(u16 h) { return __uint_as_float(((unsigned)h) << 16); }

DEVFN void gl_lds16(const void* g, void* l) {  // async global->LDS, 16B/lane
  __builtin_amdgcn_global_load_lds(
      (const __attribute__((address_space(1))) unsigned int*)g,
      (__attribute__((address_space(3))) unsigned int*)l, 16, 0, 0);
}

DEVFN f32x4 mfma16(s16x8 a, s16x8 b, f32x4 c) {
  return __builtin_amdgcn_mfma_f32_16x16x32_bf16(a, b, c, 0, 0, 0);
}

// ---------------------------------------------------------------- fused prologue
// grid (2048, 6), 256 thr. Tasks by blockIdx.y (all independent; xT reads f32 x):
//  0: cvt x   -> xb  (bf16)        1..3: cvt Wq/Wk/Wv -> Wqb/Wkb/Wvb (Wq scaled)
//  4: transpose Wo f32[4096][512] -> WoT bf16 [512][4096]   (512 blocks)
//  5: transpose x  f32[4][1024][512] -> xT bf16 [4][512][1024] (512 blocks)
__global__ void k_prep(const float* __restrict__ x, const float* __restrict__ Wq,
                       const float* __restrict__ Wk, const float* __restrict__ Wv,
                       const float* __restrict__ Wo, u16* __restrict__ ws,
                       float qscale) {
  __shared__ float tile[64][65];
  const int z = blockIdx.y, bid = blockIdx.x, tid = threadIdx.x;
  if (z < 4) {
    const float4* src = (z == 0) ? (const float4*)x : (z == 1) ? (const float4*)Wq
                      : (z == 2) ? (const float4*)Wk : (const float4*)Wv;
    const float scale = (z == 1) ? qscale : 1.f;
    u16* d = (z == 0) ? ws : ws + 2097152 + (size_t)z * 2097152;  // 0,4M,6M,8M
    int i = bid * 256 + tid;
    float4 v = src[i];
    s16x4 o;
    o[0] = (short)f2bf(v.x * scale); o[1] = (short)f2bf(v.y * scale);
    o[2] = (short)f2bf(v.z * scale); o[3] = (short)f2bf(v.w * scale);
    *(s16x4*)(d + (size_t)i * 4) = o;
    return;
  }
  if (bid >= 512) return;
  const int c = tid & 63, r4 = tid >> 6;
  if (z == 4) {  // Wo transpose: k0 x n0 tiles (K=4096, N=512)
    const int k0 = (bid & 63) * 64, n0 = (bid >> 6) * 64;
    u16* WoT = ws + 10485760;
#pragma unroll
    for (int i = 0; i < 16; ++i) {
      int r = i * 4 + r4;
      tile[r][c] = Wo[(size_t)(k0 + r) * 512 + n0 + c];
    }
    __syncthreads();
#pragma unroll
    for (int i = 0; i < 16; ++i) {
      int r = i * 4 + r4;
      WoT[(size_t)(n0 + r) * 4096 + k0 + c] = f2bf(tile[c][r]);
    }
  } else {  // x transpose: per-b 1024x512 -> 512x1024
    const int bz = bid >> 7, r0 = (bid & 15) * 64, c0 = ((bid >> 4) & 7) * 64;
    u16* xT = ws + 2097152;
#pragma unroll
    for (int i = 0; i < 16; ++i) {
      int r = i * 4 + r4;
      tile[r][c] = x[(size_t)(bz * 1024 + r0 + r) * 512 + c0 + c];
    }
    __syncthreads();
#pragma unroll
    for (int i = 0; i < 16; ++i) {
      int r = i * 4 + r4;
      xT[(size_t)bz * 524288 + (size_t)(c0 + r) * 1024 + r0 + c] = f2bf(tile[c][r]);
    }
  }
}

// ---------------------------------------------------------------- batched GEMM: 256x128 tile, 8 waves
// T1 XCD-chunked swizzle + T2 src/read chunk swizzle (0 conflicts, r9) + T4
// 3-buffer counted-vmcnt + T3-lite PHASE-SPLIT (r14): each K-32 step is 2
// barrier-fenced phases {ds_read subset + stage subset -> bar -> setprio + 8
// MFMA + setprio -> bar}. Breaks the 8-wave lockstep (m196/m230 interleave;
// enables T5 per m218b); 4 barriers per 32-K = m201's 1-per-8K density.
// Batch via bz: offset += (bz>>3)*s?b + (bz&7)*s?h.
// EPI 0: C bf16;  1: C f32+bias;  2: C f32 raw (split-K partial).
// CAUSAL: skip when col0 >= row0+256.
// VARK: Klim = row0+256, by flipped (heavy strips dispatch first).
template <int EPI, int CAUSAL, int VARK>
__global__ void __launch_bounds__(512, 2) k_gemm2(
    const u16* __restrict__ A, const u16* __restrict__ Bt,
    void* __restrict__ Cp, const float* __restrict__ bias,
    int K, int lda, int ldb, int ldc,
    size_t sAb, size_t sAh, size_t sBb, size_t sBh, size_t sCb, size_t sCh) {
  constexpr int BM = 256, BN = 128, MR = 4, NR = 4;
  constexpr int LPT = 3;                          // 24 chunks / 8 waves
  constexpr int ABUF = BM * 32, BBUF = BN * 32;   // 8192 / 4096 u16
  // ---- T1 block-id swizzle
  const unsigned nx = gridDim.x, ny = gridDim.y;
  const unsigned nwg = nx * ny * gridDim.z;
  const unsigned L = blockIdx.x + nx * (blockIdx.y + ny * blockIdx.z);
  const unsigned o = (nwg & 7) ? L : ((L & 7) * (nwg >> 3) + (L >> 3));
  const unsigned bx = o % nx, o2 = o / nx;
  unsigned by = o2 % ny;
  const unsigned bz = o2 / ny;
  if (VARK) by = (ny - 1) - by;  // heavy-first dispatch order

  const int row0 = by * BM, col0 = bx * BN;
  if (CAUSAL && col0 >= row0 + BM) return;
  __shared__ alignas(16) u16 Alds[3 * ABUF];
  __shared__ alignas(16) u16 Blds[3 * BBUF];
  const int tid = threadIdx.x, lane = tid & 63, wv = tid >> 6;
  const int wr = wv >> 1, wc = wv & 1;             // 4 x 2 wave grid
  const int zb = bz >> 3, zh = bz & 7;
  const char* Ab = (const char*)(A + (size_t)zb * sAb + (size_t)zh * sAh);
  const char* Bb = (const char*)(Bt + (size_t)zb * sBb + (size_t)zh * sBh);
  const size_t coff = (size_t)zb * sCb + (size_t)zh * sCh;
  const int Klim = VARK ? (row0 + BM) : K;
  const int ntiles = Klim >> 5;
  const f32x4 zero4 = {0.f, 0.f, 0.f, 0.f};

  // staging: 24 x 1KB chunks (A:0..15, B:16..23), 3 per wave; source 16B-chunk
  // XOR-swizzled by rowlocal bits 1-2 ((lane>>3)&3) for a conflict-free read.
  const int scb = (((lane & 3) ^ ((lane >> 3) & 3))) * 16;
  auto stage1 = [&](int buf, int k0, int j) {  // one chunk (j = 0..2)
    char* abase = (char*)(Alds + buf * ABUF);
    char* bbase = (char*)(Blds + buf * BBUF);
    int ch = wv * 3 + j;
    if (ch < 16) {
      int r = ch * 16 + (lane >> 2);
      gl_lds16(Ab + ((size_t)(row0 + r) * lda + k0) * 2 + scb, abase + ch * 1024);
    } else {
      int r = (ch - 16) * 16 + (lane >> 2);
      gl_lds16(Bb + ((size_t)(col0 + r) * ldb + k0) * 2 + scb,
               bbase + (ch - 16) * 1024);
    }
  };
  auto stageAll = [&](int buf, int k0) {
#pragma unroll
    for (int j = 0; j < 3; ++j) stage1(buf, k0, j);
  };

  f32x4 acc[MR][NR];
#pragma unroll
  for (int m = 0; m < MR; ++m)
#pragma unroll
    for (int n = 0; n < NR; ++n) acc[m][n] = zero4;

  stageAll(0, 0);
  if (ntiles > 1) stageAll(1, 32);

  const int rcb = (((lane >> 4) ^ ((lane >> 1) & 3)) & 3) * 16;

  int t = 0;
  for (int k0 = 0; k0 < Klim; k0 += 32, ++t) {
    if (t + 1 < ntiles)
      asm volatile("s_waitcnt vmcnt(%0)" :: "i"(LPT) : "memory");
    else
      asm volatile("s_waitcnt vmcnt(0)" ::: "memory");
    __builtin_amdgcn_s_barrier();              // tile t resident for all waves
    __builtin_amdgcn_sched_barrier(0);
    const char* abase = (const char*)(Alds + (t % 3) * ABUF);
    const char* bbase = (const char*)(Blds + (t % 3) * BBUF);
    s16x8 af[MR], bfr[NR];
    // ---- phase A: A-frags + B-frags 0/1, 2 stage chunks, MFMA n0-1
#pragma unroll
    for (int m = 0; m < MR; ++m)
      af[m] = *(const s16x8*)(abase +
               (wr * 64 + m * 16 + (lane & 15)) * 64 + rcb);
#pragma unroll
    for (int n = 0; n < 2; ++n)
      bfr[n] = *(const s16x8*)(bbase +
                (wc * 64 + n * 16 + (lane & 15)) * 64 + rcb);
    if (t + 2 < ntiles) { stage1((t + 2) % 3, k0 + 64, 0); stage1((t + 2) % 3, k0 + 64, 1); }
    __builtin_amdgcn_s_barrier();
    __builtin_amdgcn_sched_barrier(0);
    __builtin_amdgcn_s_setprio(1);
#pragma unroll
    for (int m = 0; m < MR; ++m)
#pragma unroll
      for (int n = 0; n < 2; ++n) acc[m][n] = mfma16(af[m], bfr[n], acc[m][n]);
    __builtin_amdgcn_s_setprio(0);
    __builtin_amdgcn_s_barrier();
    __builtin_amdgcn_sched_barrier(0);
    // ---- phase B: B-frags 2/3, 1 stage chunk, MFMA n2-3
#pragma unroll
    for (int n = 2; n < 4; ++n)
      bfr[n] = *(const s16x8*)(bbase +
                (wc * 64 + n * 16 + (lane & 15)) * 64 + rcb);
    if (t + 2 < ntiles) stage1((t + 2) % 3, k0 + 64, 2);
    __builtin_amdgcn_s_barrier();
    __builtin_amdgcn_sched_barrier(0);
    __builtin_amdgcn_s_setprio(1);
#pragma unroll
    for (int m = 0; m < MR; ++m)
#pragma unroll
      for (int n = 2; n < 4; ++n) acc[m][n] = mfma16(af[m], bfr[n], acc[m][n]);
    __builtin_amdgcn_s_setprio(0);
  }
#pragma unroll
  for (int m = 0; m < MR; ++m)
#pragma unroll
    for (int n = 0; n < NR; ++n)
#pragma unroll
      for (int i = 0; i < 4; ++i) {
        int r = row0 + wr * 64 + m * 16 + (lane >> 4) * 4 + i;
        int c = col0 + wc * 64 + n * 16 + (lane & 15);
        if (EPI == 0)
          ((u16*)Cp)[coff + (size_t)r * ldc + c] = f2bf(acc[m][n][i]);
        else if (EPI == 1)
          ((float*)Cp)[coff + (size_t)r * ldc + c] = acc[m][n][i] + bias[c];
        else
          ((float*)Cp)[coff + (size_t)r * ldc + c] = acc[m][n][i];
      }
}

// ---------------------------------------------------------------- causal row softmax
// S = [32 bh][1024 q][1024 k] bf16. One wave per row; masks by column index.
// Rows q<512 touch only the first 512 columns (PV's VARK never reads beyond).
__global__ void __launch_bounds__(256) k_softmax(u16* __restrict__ S) {
  const int tid = threadIdx.x, lane = tid & 63, w = tid >> 6;
  const int row = blockIdx.x * 4 + w;
  const int q = row & 1023;
  u16* rowp = S + (size_t)(row >> 10) * 1048576 + (size_t)q * 1024;
  const int c0 = lane * 8, c1 = 512 + lane * 8;
  const bool hi = (q >= 512);
  s16x8 v0 = *(const s16x8*)(rowp + c0);
  s16x8 v1 = {};
  if (hi) v1 = *(const s16x8*)(rowp + c1);
  float f[16];
#pragma unroll
  for (int j = 0; j < 8; ++j) {
    f[j]     = (c0 + j <= q)       ? bf2f((u16)v0[j]) : -3e38f;
    f[8 + j] = (hi && c1 + j <= q) ? bf2f((u16)v1[j]) : -3e38f;
  }
  float m = f[0];
#pragma unroll
  for (int j = 1; j < 16; ++j) m = fmaxf(m, f[j]);
  m = fmaxf(m, __shfl_xor(m, 1));
  m = fmaxf(m, __shfl_xor(m, 2));
  m = fmaxf(m, __shfl_xor(m, 4));
  m = fmaxf(m, __shfl_xor(m, 8));
  m = fmaxf(m, __shfl_xor(m, 16));
  m = fmaxf(m, __shfl_xor(m, 32));
  float sum = 0.f;
#pragma unroll
  for (int j = 0; j < 16; ++j) { f[j] = __expf(f[j] - m); sum += f[j]; }
  sum += __shfl_xor(sum, 1);
  sum += __shfl_xor(sum, 2);
  sum += __shfl_xor(sum, 4);
  sum += __shfl_xor(sum, 8);
  sum += __shfl_xor(sum, 16);
  sum += __shfl_xor(sum, 32);
  const float inv = 1.f / sum;
#pragma unroll
  for (int j = 0; j < 8; ++j) {
    v0[j] = (short)f2bf(f[j] * inv);
    v1[j] = (short)f2bf(f[8 + j] * inv);
  }
  *(s16x8*)(rowp + c0) = v0;
  if (hi) *(s16x8*)(rowp + c1) = v1;
}

// ---------------------------------------------------------------- split-K=8 reduce (+bias)
__global__ void k_reduce8(const float4* __restrict__ P, const float4* __restrict__ bias,
                          float4* __restrict__ out, int n4) {
  int i = blockIdx.x * 256 + threadIdx.x;
  if (i >= n4) return;
  float4 bb = bias[i & 127];
  float sx = bb.x, sy = bb.y, sz = bb.z, sw = bb.w;
#pragma unroll
  for (int j = 0; j < 8; ++j) {
    float4 a = P[i + (size_t)j * 524288];
    sx += a.x; sy += a.y; sz += a.z; sw += a.w;
  }
  float4 o2;
  o2.x = sx; o2.y = sy; o2.z = sz; o2.w = sw;
  out[i] = o2;
}

// ---------------------------------------------------------------- launch
// Head-factored pipeline: G_h = Wq̂_h Wk_h^T, Wvo_h = Wv_h Wo_h fold the K/V
// projections:  y = x@G^T -> S = y@x^T (causal) -> softmax -> Z = P@x ->
// out = Z@WvoT^T + bo (split-K=8 + reduce).  8 launches total.
// G is stored H-INTERLEAVED [512][4096] (same C geometry as WvoT) so G and Wvo
// compute as ONE batched launch (zb selects the task via the batch strides).
// Workspace (u16 elems):
//   xb 0 | xT 2M | Wqb 4M | Wkb 6M | Wvb 8M | WoT 10M | G 12M | WvoT 14M
//   y 16M..32M | S 32M..64M (fp32 split-K partials alias S after Z) | Z 64M..80M
extern "C" void kernel_launch(void* const* d_in, const int* in_sizes, int n_in,
                              void* d_out, int out_size, void* d_ws, size_t ws_size,
                              hipStream_t stream) {
  (void)in_sizes; (void)n_in; (void)out_size; (void)ws_size;
  const float* x  = (const float*)d_in[0];
  const float* Wq = (const float*)d_in[1];
  const float* Wk = (const float*)d_in[2];
  const float* Wv = (const float*)d_in[3];
  const float* Wo = (const float*)d_in[4];
  const float* bo = (const float*)d_in[5];
  float* out = (float*)d_out;

  u16* ws   = (u16*)d_ws;
  u16* xb   = ws;                      // [4096][512]
  u16* xT   = ws + 2097152;            // [4][512][1024]
  u16* Wqb  = ws + 4194304;            // [512][4096] (scaled by 1/sqrt(512))
  u16* Wkb  = ws + 6291456;            // [512][4096]
  u16* Wvb  = ws + 8388608;            // [512][4096]
  u16* WoT  = ws + 10485760;           // [512][4096]
  u16* G    = ws + 12582912;           // [512][4096]  Gw[e'][h*512+e]
  u16* WvoT = ws + 14680064;           // [512][4096]
  u16* y    = ws + 16777216;           // [8][4096][512]
  u16* S    = ws + 33554432;           // [32][1024][1024]
  u16* Z    = ws + 67108864;           // [4096][4096]
  float* Pp = (float*)(ws + 33554432); // 8 x [4096][512] fp32 partials (alias S, dead after Z)

  const float qscale = 0.044194173824159216f;  // 1/sqrt(512)

  // ---- fused prologue (1 launch)
  k_prep<<<dim3(2048, 6), 256, 0, stream>>>(x, Wq, Wk, Wv, Wo, ws, qscale);

  // ---- G (zb=0) + Wvo (zb=1) as one batched launch, 128 blocks
  k_gemm2<0, 0, 0><<<dim3(4, 2, 16), 512, 0, stream>>>(
      Wkb, Wqb, (void*)G, nullptr, 512, 4096, 4096, 4096,
      4194304, 512, 4194304, 512, 2097152, 512);

  // ---- y_h = x @ G_h^T   [8][4096][512]   (B rows at ldb=4096, per-h offset 512)
  k_gemm2<0, 0, 0><<<dim3(4, 16, 8), 512, 0, stream>>>(
      xb, G, (void*)y, nullptr, 512, 512, 4096, 512,
      0, 0, 0, 512, 0, 2097152);

  // ---- S = y_h @ x_b^T  (causal 256-row strips), batched over 32 bh
  k_gemm2<0, 1, 0><<<dim3(8, 4, 32), 512, 0, stream>>>(
      y, xb, (void*)S, nullptr, 512, 512, 512, 1024,
      524288, 2097152, 524288, 0, 8388608, 1048576);

  // ---- causal softmax
  k_softmax<<<8192, 256, 0, stream>>>(S);

  // ---- Z = P @ x_b  (VARK heavy-first: 256-row strip by uses (by+1)*256 keys)
  k_gemm2<0, 0, 1><<<dim3(4, 4, 32), 512, 0, stream>>>(
      S, xT, (void*)Z, nullptr, 1024, 1024, 1024, 4096,
      8388608, 1048576, 524288, 0, 4194304, 512);

  // ---- out = Z @ WvoT^T + bo, split-K=8 (z = k-chunk via stride trick)
  k_gemm2<2, 0, 0><<<dim3(4, 16, 8), 512, 0, stream>>>(
      Z, WvoT, (void*)Pp, nullptr, 512, 4096, 4096, 512,
      0, 512, 0, 512, 0, 2097152);
  k_reduce8<<<2048, 256, 0, stream>>>((const float4*)Pp, (const float4*)bo,
                                      (float4*)out, 524288);
}

// Round 15
// 174.101 us; speedup vs baseline: 1.1000x; 1.1000x over previous
//
#include <hip/hip_runtime.h>
#include <hip/hip_bf16.h>

typedef unsigned short u16;
typedef __attribute__((ext_vector_type(4))) float f32x4;
typedef __attribute__((ext_vector_type(8))) short s16x8;  // 8 x bf16 (4 VGPRs)
typedef __attribute__((ext_vector_type(4))) short s16x4;

#define DEVFN static __device__ __forceinline__

DEVFN u16 f2bf(float f) {  // fp32 -> bf16, round-nearest-even
  unsigned u = __float_as_uint(f);
  return (u16)((u + 0x7fffu + ((u >> 16) & 1u)) >> 16);
}
DEVFN float bf2f(u16 h) { return __uint_as_float(((unsigned)h) << 16); }

DEVFN void gl_lds16(const void* g, void* l) {  // async global->LDS, 16B/lane
  __builtin_amdgcn_global_load_lds(
      (const __attribute__((address_space(1))) unsigned int*)g,
      (__attribute__((address_space(3))) unsigned int*)l, 16, 0, 0);
}

DEVFN f32x4 mfma16(s16x8 a, s16x8 b, f32x4 c) {
  return __builtin_amdgcn_mfma_f32_16x16x32_bf16(a, b, c, 0, 0, 0);
}

// ---------------------------------------------------------------- fused prologue
// grid (2048, 6), 256 thr. Tasks by blockIdx.y (all independent; xT reads f32 x):
//  0: cvt x   -> xb  (bf16)        1..3: cvt Wq/Wk/Wv -> Wqb/Wkb/Wvb (Wq scaled)
//  4: transpose Wo f32[4096][512] -> WoT bf16 [512][4096]   (512 blocks)
//  5: transpose x  f32[4][1024][512] -> xT bf16 [4][512][1024] (512 blocks)
__global__ void k_prep(const float* __restrict__ x, const float* __restrict__ Wq,
                       const float* __restrict__ Wk, const float* __restrict__ Wv,
                       const float* __restrict__ Wo, u16* __restrict__ ws,
                       float qscale) {
  __shared__ float tile[64][65];
  const int z = blockIdx.y, bid = blockIdx.x, tid = threadIdx.x;
  if (z < 4) {
    const float4* src = (z == 0) ? (const float4*)x : (z == 1) ? (const float4*)Wq
                      : (z == 2) ? (const float4*)Wk : (const float4*)Wv;
    const float scale = (z == 1) ? qscale : 1.f;
    u16* d = (z == 0) ? ws : ws + 2097152 + (size_t)z * 2097152;  // 0,4M,6M,8M
    int i = bid * 256 + tid;
    float4 v = src[i];
    s16x4 o;
    o[0] = (short)f2bf(v.x * scale); o[1] = (short)f2bf(v.y * scale);
    o[2] = (short)f2bf(v.z * scale); o[3] = (short)f2bf(v.w * scale);
    *(s16x4*)(d + (size_t)i * 4) = o;
    return;
  }
  if (bid >= 512) return;
  const int c = tid & 63, r4 = tid >> 6;
  if (z == 4) {  // Wo transpose: k0 x n0 tiles (K=4096, N=512)
    const int k0 = (bid & 63) * 64, n0 = (bid >> 6) * 64;
    u16* WoT = ws + 10485760;
#pragma unroll
    for (int i = 0; i < 16; ++i) {
      int r = i * 4 + r4;
      tile[r][c] = Wo[(size_t)(k0 + r) * 512 + n0 + c];
    }
    __syncthreads();
#pragma unroll
    for (int i = 0; i < 16; ++i) {
      int r = i * 4 + r4;
      WoT[(size_t)(n0 + r) * 4096 + k0 + c] = f2bf(tile[c][r]);
    }
  } else {  // x transpose: per-b 1024x512 -> 512x1024
    const int bz = bid >> 7, r0 = (bid & 15) * 64, c0 = ((bid >> 4) & 7) * 64;
    u16* xT = ws + 2097152;
#pragma unroll
    for (int i = 0; i < 16; ++i) {
      int r = i * 4 + r4;
      tile[r][c] = x[(size_t)(bz * 1024 + r0 + r) * 512 + c0 + c];
    }
    __syncthreads();
#pragma unroll
    for (int i = 0; i < 16; ++i) {
      int r = i * 4 + r4;
      xT[(size_t)bz * 524288 + (size_t)(c0 + r) * 1024 + r0 + c] = f2bf(tile[c][r]);
    }
  }
}

// ---------------------------------------------------------------- batched GEMM: 256x128 tile, 8 waves
// r13-proven body: T1 XCD-chunked swizzle + T2 src/read chunk swizzle (0
// conflicts, r9) + T4 3-buffer counted-vmcnt pipeline, single-phase K-step.
// (r14's phase-split regressed -6%; reverted.)
// 8 waves = 4 row-groups x 2 col-groups; each wave owns 64x64 (16 MFMA/step).
// Batch via bz: offset += (bz>>3)*s?b + (bz&7)*s?h.
// EPI 0: C bf16;  1: C f32+bias;  2: C f32 raw (split-K partial).
// CAUSAL: skip when col0 >= row0+256.
// VARK: Klim = row0+256, by flipped (heavy strips dispatch first).
template <int EPI, int CAUSAL, int VARK>
__global__ void __launch_bounds__(512, 2) k_gemm2(
    const u16* __restrict__ A, const u16* __restrict__ Bt,
    void* __restrict__ Cp, const float* __restrict__ bias,
    int K, int lda, int ldb, int ldc,
    size_t sAb, size_t sAh, size_t sBb, size_t sBh, size_t sCb, size_t sCh) {
  constexpr int BM = 256, BN = 128, MR = 4, NR = 4;
  constexpr int LPT = 3;                          // 24 chunks / 8 waves
  constexpr int ABUF = BM * 32, BBUF = BN * 32;   // 8192 / 4096 u16
  // ---- T1 block-id swizzle
  const unsigned nx = gridDim.x, ny = gridDim.y;
  const unsigned nwg = nx * ny * gridDim.z;
  const unsigned L = blockIdx.x + nx * (blockIdx.y + ny * blockIdx.z);
  const unsigned o = (nwg & 7) ? L : ((L & 7) * (nwg >> 3) + (L >> 3));
  const unsigned bx = o % nx, o2 = o / nx;
  unsigned by = o2 % ny;
  const unsigned bz = o2 / ny;
  if (VARK) by = (ny - 1) - by;  // heavy-first dispatch order

  const int row0 = by * BM, col0 = bx * BN;
  if (CAUSAL && col0 >= row0 + BM) return;
  __shared__ alignas(16) u16 Alds[3 * ABUF];
  __shared__ alignas(16) u16 Blds[3 * BBUF];
  const int tid = threadIdx.x, lane = tid & 63, wv = tid >> 6;
  const int wr = wv >> 1, wc = wv & 1;             // 4 x 2 wave grid
  const int zb = bz >> 3, zh = bz & 7;
  const char* Ab = (const char*)(A + (size_t)zb * sAb + (size_t)zh * sAh);
  const char* Bb = (const char*)(Bt + (size_t)zb * sBb + (size_t)zh * sBh);
  const size_t coff = (size_t)zb * sCb + (size_t)zh * sCh;
  const int Klim = VARK ? (row0 + BM) : K;
  const int ntiles = Klim >> 5;
  const f32x4 zero4 = {0.f, 0.f, 0.f, 0.f};

  // staging: 24 x 1KB chunks (A:0..15, B:16..23), 3 per wave; source 16B-chunk
  // XOR-swizzled by rowlocal bits 1-2 ((lane>>3)&3) for a conflict-free read.
  const int scb = (((lane & 3) ^ ((lane >> 3) & 3))) * 16;
  auto stage = [&](int buf, int k0) {
    char* abase = (char*)(Alds + buf * ABUF);
    char* bbase = (char*)(Blds + buf * BBUF);
#pragma unroll
    for (int j = 0; j < 3; ++j) {
      int ch = wv * 3 + j;
      if (ch < 16) {
        int r = ch * 16 + (lane >> 2);
        gl_lds16(Ab + ((size_t)(row0 + r) * lda + k0) * 2 + scb, abase + ch * 1024);
      } else {
        int r = (ch - 16) * 16 + (lane >> 2);
        gl_lds16(Bb + ((size_t)(col0 + r) * ldb + k0) * 2 + scb,
                 bbase + (ch - 16) * 1024);
      }
    }
  };

  f32x4 acc[MR][NR];
#pragma unroll
  for (int m = 0; m < MR; ++m)
#pragma unroll
    for (int n = 0; n < NR; ++n) acc[m][n] = zero4;

  stage(0, 0);
  if (ntiles > 1) stage(1, 32);

  const int rcb = (((lane >> 4) ^ ((lane >> 1) & 3)) & 3) * 16;

  int t = 0;
  for (int k0 = 0; k0 < Klim; k0 += 32, ++t) {
    if (t + 1 < ntiles)
      asm volatile("s_waitcnt vmcnt(%0)" :: "i"(LPT) : "memory");
    else
      asm volatile("s_waitcnt vmcnt(0)" ::: "memory");
    __builtin_amdgcn_s_barrier();
    asm volatile("" ::: "memory");  // pin ds_reads below the barrier
    if (t + 2 < ntiles) stage((t + 2) % 3, k0 + 64);
    const char* abase = (const char*)(Alds + (t % 3) * ABUF);
    const char* bbase = (const char*)(Blds + (t % 3) * BBUF);
    s16x8 af[MR], bfr[NR];
#pragma unroll
    for (int m = 0; m < MR; ++m)
      af[m] = *(const s16x8*)(abase +
               (wr * 64 + m * 16 + (lane & 15)) * 64 + rcb);
#pragma unroll
    for (int n = 0; n < NR; ++n)
      bfr[n] = *(const s16x8*)(bbase +
                (wc * 64 + n * 16 + (lane & 15)) * 64 + rcb);
    __builtin_amdgcn_s_setprio(1);
#pragma unroll
    for (int m = 0; m < MR; ++m)
#pragma unroll
      for (int n = 0; n < NR; ++n) acc[m][n] = mfma16(af[m], bfr[n], acc[m][n]);
    __builtin_amdgcn_s_setprio(0);
  }
#pragma unroll
  for (int m = 0; m < MR; ++m)
#pragma unroll
    for (int n = 0; n < NR; ++n)
#pragma unroll
      for (int i = 0; i < 4; ++i) {
        int r = row0 + wr * 64 + m * 16 + (lane >> 4) * 4 + i;
        int c = col0 + wc * 64 + n * 16 + (lane & 15);
        if (EPI == 0)
          ((u16*)Cp)[coff + (size_t)r * ldc + c] = f2bf(acc[m][n][i]);
        else if (EPI == 1)
          ((float*)Cp)[coff + (size_t)r * ldc + c] = acc[m][n][i] + bias[c];
        else
          ((float*)Cp)[coff + (size_t)r * ldc + c] = acc[m][n][i];
      }
}

// ---------------------------------------------------------------- causal row softmax
// S = [32 bh][1024 q][1024 k] bf16. One wave per row; masks by column index.
// Rows q<512 touch only the first 512 columns (PV's VARK never reads beyond).
__global__ void __launch_bounds__(256) k_softmax(u16* __restrict__ S) {
  const int tid = threadIdx.x, lane = tid & 63, w = tid >> 6;
  const int row = blockIdx.x * 4 + w;
  const int q = row & 1023;
  u16* rowp = S + (size_t)(row >> 10) * 1048576 + (size_t)q * 1024;
  const int c0 = lane * 8, c1 = 512 + lane * 8;
  const bool hi = (q >= 512);
  s16x8 v0 = *(const s16x8*)(rowp + c0);
  s16x8 v1 = {};
  if (hi) v1 = *(const s16x8*)(rowp + c1);
  float f[16];
#pragma unroll
  for (int j = 0; j < 8; ++j) {
    f[j]     = (c0 + j <= q)       ? bf2f((u16)v0[j]) : -3e38f;
    f[8 + j] = (hi && c1 + j <= q) ? bf2f((u16)v1[j]) : -3e38f;
  }
  float m = f[0];
#pragma unroll
  for (int j = 1; j < 16; ++j) m = fmaxf(m, f[j]);
  m = fmaxf(m, __shfl_xor(m, 1));
  m = fmaxf(m, __shfl_xor(m, 2));
  m = fmaxf(m, __shfl_xor(m, 4));
  m = fmaxf(m, __shfl_xor(m, 8));
  m = fmaxf(m, __shfl_xor(m, 16));
  m = fmaxf(m, __shfl_xor(m, 32));
  float sum = 0.f;
#pragma unroll
  for (int j = 0; j < 16; ++j) { f[j] = __expf(f[j] - m); sum += f[j]; }
  sum += __shfl_xor(sum, 1);
  sum += __shfl_xor(sum, 2);
  sum += __shfl_xor(sum, 4);
  sum += __shfl_xor(sum, 8);
  sum += __shfl_xor(sum, 16);
  sum += __shfl_xor(sum, 32);
  const float inv = 1.f / sum;
#pragma unroll
  for (int j = 0; j < 8; ++j) {
    v0[j] = (short)f2bf(f[j] * inv);
    v1[j] = (short)f2bf(f[8 + j] * inv);
  }
  *(s16x8*)(rowp + c0) = v0;
  if (hi) *(s16x8*)(rowp + c1) = v1;
}

// ---------------------------------------------------------------- split-K=4 reduce (+bias)
__global__ void k_reduce4(const float4* __restrict__ P, const float4* __restrict__ bias,
                          float4* __restrict__ out, int n4) {
  int i = blockIdx.x * 256 + threadIdx.x;
  if (i >= n4) return;
  float4 a = P[i], b = P[i + 524288], c = P[i + 1048576], d = P[i + 1572864];
  float4 bb = bias[i & 127];  // 512 cols / 4 = 128 float4 per row
  float4 o;
  o.x = a.x + b.x + c.x + d.x + bb.x;
  o.y = a.y + b.y + c.y + d.y + bb.y;
  o.z = a.z + b.z + c.z + d.z + bb.z;
  o.w = a.w + b.w + c.w + d.w + bb.w;
  out[i] = o;
}

// ---------------------------------------------------------------- launch
// Head-factored pipeline: G_h = Wq̂_h Wk_h^T, Wvo_h = Wv_h Wo_h fold the K/V
// projections:  y = x@G^T -> S = y@x^T (causal) -> softmax -> Z = P@x ->
// out = Z@WvoT^T + bo (split-K=4 + reduce).  8 launches total.
// G is stored H-INTERLEAVED [512][4096] (same C geometry as WvoT) so G and Wvo
// compute as ONE batched launch (zb selects the task via the batch strides).
// Workspace (u16 elems):
//   xb 0 | xT 2M | Wqb 4M | Wkb 6M | Wvb 8M | WoT 10M | G 12M | WvoT 14M
//   y 16M..32M | S 32M..64M (fp32 split-K partials alias S after Z) | Z 64M..80M
extern "C" void kernel_launch(void* const* d_in, const int* in_sizes, int n_in,
                              void* d_out, int out_size, void* d_ws, size_t ws_size,
                              hipStream_t stream) {
  (void)in_sizes; (void)n_in; (void)out_size; (void)ws_size;
  const float* x  = (const float*)d_in[0];
  const float* Wq = (const float*)d_in[1];
  const float* Wk = (const float*)d_in[2];
  const float* Wv = (const float*)d_in[3];
  const float* Wo = (const float*)d_in[4];
  const float* bo = (const float*)d_in[5];
  float* out = (float*)d_out;

  u16* ws   = (u16*)d_ws;
  u16* xb   = ws;                      // [4096][512]
  u16* xT   = ws + 2097152;            // [4][512][1024]
  u16* Wqb  = ws + 4194304;            // [512][4096] (scaled by 1/sqrt(512))
  u16* Wkb  = ws + 6291456;            // [512][4096]
  u16* Wvb  = ws + 8388608;            // [512][4096]
  u16* WoT  = ws + 10485760;           // [512][4096]
  u16* G    = ws + 12582912;           // [512][4096]  Gw[e'][h*512+e]
  u16* WvoT = ws + 14680064;           // [512][4096]
  u16* y    = ws + 16777216;           // [8][4096][512]
  u16* S    = ws + 33554432;           // [32][1024][1024]
  u16* Z    = ws + 67108864;           // [4096][4096]
  float* Pp = (float*)(ws + 33554432); // 4 x [4096][512] fp32 partials (alias S, dead after Z)

  const float qscale = 0.044194173824159216f;  // 1/sqrt(512)

  // ---- fused prologue (1 launch)
  k_prep<<<dim3(2048, 6), 256, 0, stream>>>(x, Wq, Wk, Wv, Wo, ws, qscale);

  // ---- G (zb=0) + Wvo (zb=1) as one batched launch, 128 blocks
  k_gemm2<0, 0, 0><<<dim3(4, 2, 16), 512, 0, stream>>>(
      Wkb, Wqb, (void*)G, nullptr, 512, 4096, 4096, 4096,
      4194304, 512, 4194304, 512, 2097152, 512);

  // ---- y_h = x @ G_h^T   [8][4096][512]   (B rows at ldb=4096, per-h offset 512)
  k_gemm2<0, 0, 0><<<dim3(4, 16, 8), 512, 0, stream>>>(
      xb, G, (void*)y, nullptr, 512, 512, 4096, 512,
      0, 0, 0, 512, 0, 2097152);

  // ---- S = y_h @ x_b^T  (causal 256-row strips), batched over 32 bh
  k_gemm2<0, 1, 0><<<dim3(8, 4, 32), 512, 0, stream>>>(
      y, xb, (void*)S, nullptr, 512, 512, 512, 1024,
      524288, 2097152, 524288, 0, 8388608, 1048576);

  // ---- causal softmax
  k_softmax<<<8192, 256, 0, stream>>>(S);

  // ---- Z = P @ x_b  (VARK heavy-first: 256-row strip by uses (by+1)*256 keys)
  k_gemm2<0, 0, 1><<<dim3(4, 4, 32), 512, 0, stream>>>(
      S, xT, (void*)Z, nullptr, 1024, 1024, 1024, 4096,
      8388608, 1048576, 524288, 0, 4194304, 512);

  // ---- out = Z @ WvoT^T + bo, split-K=4 (zh = k-chunk via stride trick; K=1024/chunk)
  k_gemm2<2, 0, 0><<<dim3(4, 16, 4), 512, 0, stream>>>(
      Z, WvoT, (void*)Pp, nullptr, 1024, 4096, 4096, 512,
      0, 1024, 0, 1024, 0, 2097152);
  k_reduce4<<<2048, 256, 0, stream>>>((const float4*)Pp, (const float4*)bo,
                                      (float4*)out, 524288);
}

// Round 16
// 170.949 us; speedup vs baseline: 1.1202x; 1.0184x over previous
//
#include <hip/hip_runtime.h>
#include <hip/hip_bf16.h>

typedef unsigned short u16;
typedef __attribute__((ext_vector_type(4))) float f32x4;
typedef __attribute__((ext_vector_type(8))) short s16x8;  // 8 x bf16 (4 VGPRs)
typedef __attribute__((ext_vector_type(4))) short s16x4;

#define DEVFN static __device__ __forceinline__

DEVFN u16 f2bf(float f) {  // fp32 -> bf16, round-nearest-even
  unsigned u = __float_as_uint(f);
  return (u16)((u + 0x7fffu + ((u >> 16) & 1u)) >> 16);
}
DEVFN float bf2f(u16 h) { return __uint_as_float(((unsigned)h) << 16); }

DEVFN void gl_lds16(const void* g, void* l) {  // async global->LDS, 16B/lane
  __builtin_amdgcn_global_load_lds(
      (const __attribute__((address_space(1))) unsigned int*)g,
      (__attribute__((address_space(3))) unsigned int*)l, 16, 0, 0);
}

DEVFN f32x4 mfma16(s16x8 a, s16x8 b, f32x4 c) {
  return __builtin_amdgcn_mfma_f32_16x16x32_bf16(a, b, c, 0, 0, 0);
}

// ---------------------------------------------------------------- fused prologue
// grid (2048, 6), 256 thr. Tasks by blockIdx.y (all independent; xT reads f32 x):
//  0: cvt x   -> xb  (bf16)        1..3: cvt Wq/Wk/Wv -> Wqb/Wkb/Wvb (Wq scaled)
//  4: transpose Wo f32[4096][512] -> WoT bf16 [512][4096]   (512 blocks)
//  5: transpose x  f32[4][1024][512] -> xT bf16 [4][512][1024] (512 blocks)
__global__ void k_prep(const float* __restrict__ x, const float* __restrict__ Wq,
                       const float* __restrict__ Wk, const float* __restrict__ Wv,
                       const float* __restrict__ Wo, u16* __restrict__ ws,
                       float qscale) {
  __shared__ float tile[64][65];
  const int z = blockIdx.y, bid = blockIdx.x, tid = threadIdx.x;
  if (z < 4) {
    const float4* src = (z == 0) ? (const float4*)x : (z == 1) ? (const float4*)Wq
                      : (z == 2) ? (const float4*)Wk : (const float4*)Wv;
    const float scale = (z == 1) ? qscale : 1.f;
    u16* d = (z == 0) ? ws : ws + 2097152 + (size_t)z * 2097152;  // 0,4M,6M,8M
    int i = bid * 256 + tid;
    float4 v = src[i];
    s16x4 o;
    o[0] = (short)f2bf(v.x * scale); o[1] = (short)f2bf(v.y * scale);
    o[2] = (short)f2bf(v.z * scale); o[3] = (short)f2bf(v.w * scale);
    *(s16x4*)(d + (size_t)i * 4) = o;
    return;
  }
  if (bid >= 512) return;
  const int c = tid & 63, r4 = tid >> 6;
  if (z == 4) {  // Wo transpose: k0 x n0 tiles (K=4096, N=512)
    const int k0 = (bid & 63) * 64, n0 = (bid >> 6) * 64;
    u16* WoT = ws + 10485760;
#pragma unroll
    for (int i = 0; i < 16; ++i) {
      int r = i * 4 + r4;
      tile[r][c] = Wo[(size_t)(k0 + r) * 512 + n0 + c];
    }
    __syncthreads();
#pragma unroll
    for (int i = 0; i < 16; ++i) {
      int r = i * 4 + r4;
      WoT[(size_t)(n0 + r) * 4096 + k0 + c] = f2bf(tile[c][r]);
    }
  } else {  // x transpose: per-b 1024x512 -> 512x1024
    const int bz = bid >> 7, r0 = (bid & 15) * 64, c0 = ((bid >> 4) & 7) * 64;
    u16* xT = ws + 2097152;
#pragma unroll
    for (int i = 0; i < 16; ++i) {
      int r = i * 4 + r4;
      tile[r][c] = x[(size_t)(bz * 1024 + r0 + r) * 512 + c0 + c];
    }
    __syncthreads();
#pragma unroll
    for (int i = 0; i < 16; ++i) {
      int r = i * 4 + r4;
      xT[(size_t)bz * 524288 + (size_t)(c0 + r) * 1024 + r0 + c] = f2bf(tile[c][r]);
    }
  }
}

// ---------------------------------------------------------------- batched GEMM: 256x128 tile, 8 waves
// r13-proven body: T1 XCD-chunked swizzle + T2 src/read chunk swizzle (0
// conflicts, r9) + T4 3-buffer counted-vmcnt pipeline, single-phase K-step.
// (r14's phase-split regressed -6%; reverted. 5 schedule grafts null/neg total.)
// 8 waves = 4 row-groups x 2 col-groups; each wave owns 64x64 (16 MFMA/step).
// Batch via bz: offset += (bz>>3)*s?b + (bz&7)*s?h.
// EPI 0: C bf16;  1: C f32+bias;  2: C bf16 split-K partial (r16: was f32 —
// halves partial traffic; |partial|~O(1), bf16 err ~0.004/plane, margin 3x).
// CAUSAL: skip when col0 >= row0+256.
// VARK: Klim = row0+256, by flipped (heavy strips dispatch first).
template <int EPI, int CAUSAL, int VARK>
__global__ void __launch_bounds__(512, 2) k_gemm2(
    const u16* __restrict__ A, const u16* __restrict__ Bt,
    void* __restrict__ Cp, const float* __restrict__ bias,
    int K, int lda, int ldb, int ldc,
    size_t sAb, size_t sAh, size_t sBb, size_t sBh, size_t sCb, size_t sCh) {
  constexpr int BM = 256, BN = 128, MR = 4, NR = 4;
  constexpr int LPT = 3;                          // 24 chunks / 8 waves
  constexpr int ABUF = BM * 32, BBUF = BN * 32;   // 8192 / 4096 u16
  // ---- T1 block-id swizzle
  const unsigned nx = gridDim.x, ny = gridDim.y;
  const unsigned nwg = nx * ny * gridDim.z;
  const unsigned L = blockIdx.x + nx * (blockIdx.y + ny * blockIdx.z);
  const unsigned o = (nwg & 7) ? L : ((L & 7) * (nwg >> 3) + (L >> 3));
  const unsigned bx = o % nx, o2 = o / nx;
  unsigned by = o2 % ny;
  const unsigned bz = o2 / ny;
  if (VARK) by = (ny - 1) - by;  // heavy-first dispatch order

  const int row0 = by * BM, col0 = bx * BN;
  if (CAUSAL && col0 >= row0 + BM) return;
  __shared__ alignas(16) u16 Alds[3 * ABUF];
  __shared__ alignas(16) u16 Blds[3 * BBUF];
  const int tid = threadIdx.x, lane = tid & 63, wv = tid >> 6;
  const int wr = wv >> 1, wc = wv & 1;             // 4 x 2 wave grid
  const int zb = bz >> 3, zh = bz & 7;
  const char* Ab = (const char*)(A + (size_t)zb * sAb + (size_t)zh * sAh);
  const char* Bb = (const char*)(Bt + (size_t)zb * sBb + (size_t)zh * sBh);
  const size_t coff = (size_t)zb * sCb + (size_t)zh * sCh;
  const int Klim = VARK ? (row0 + BM) : K;
  const int ntiles = Klim >> 5;
  const f32x4 zero4 = {0.f, 0.f, 0.f, 0.f};

  // staging: 24 x 1KB chunks (A:0..15, B:16..23), 3 per wave; source 16B-chunk
  // XOR-swizzled by rowlocal bits 1-2 ((lane>>3)&3) for a conflict-free read.
  const int scb = (((lane & 3) ^ ((lane >> 3) & 3))) * 16;
  auto stage = [&](int buf, int k0) {
    char* abase = (char*)(Alds + buf * ABUF);
    char* bbase = (char*)(Blds + buf * BBUF);
#pragma unroll
    for (int j = 0; j < 3; ++j) {
      int ch = wv * 3 + j;
      if (ch < 16) {
        int r = ch * 16 + (lane >> 2);
        gl_lds16(Ab + ((size_t)(row0 + r) * lda + k0) * 2 + scb, abase + ch * 1024);
      } else {
        int r = (ch - 16) * 16 + (lane >> 2);
        gl_lds16(Bb + ((size_t)(col0 + r) * ldb + k0) * 2 + scb,
                 bbase + (ch - 16) * 1024);
      }
    }
  };

  f32x4 acc[MR][NR];
#pragma unroll
  for (int m = 0; m < MR; ++m)
#pragma unroll
    for (int n = 0; n < NR; ++n) acc[m][n] = zero4;

  stage(0, 0);
  if (ntiles > 1) stage(1, 32);

  const int rcb = (((lane >> 4) ^ ((lane >> 1) & 3)) & 3) * 16;

  int t = 0;
  for (int k0 = 0; k0 < Klim; k0 += 32, ++t) {
    if (t + 1 < ntiles)
      asm volatile("s_waitcnt vmcnt(%0)" :: "i"(LPT) : "memory");
    else
      asm volatile("s_waitcnt vmcnt(0)" ::: "memory");
    __builtin_amdgcn_s_barrier();
    asm volatile("" ::: "memory");  // pin ds_reads below the barrier
    if (t + 2 < ntiles) stage((t + 2) % 3, k0 + 64);
    const char* abase = (const char*)(Alds + (t % 3) * ABUF);
    const char* bbase = (const char*)(Blds + (t % 3) * BBUF);
    s16x8 af[MR], bfr[NR];
#pragma unroll
    for (int m = 0; m < MR; ++m)
      af[m] = *(const s16x8*)(abase +
               (wr * 64 + m * 16 + (lane & 15)) * 64 + rcb);
#pragma unroll
    for (int n = 0; n < NR; ++n)
      bfr[n] = *(const s16x8*)(bbase +
                (wc * 64 + n * 16 + (lane & 15)) * 64 + rcb);
    __builtin_amdgcn_s_setprio(1);
#pragma unroll
    for (int m = 0; m < MR; ++m)
#pragma unroll
      for (int n = 0; n < NR; ++n) acc[m][n] = mfma16(af[m], bfr[n], acc[m][n]);
    __builtin_amdgcn_s_setprio(0);
  }
#pragma unroll
  for (int m = 0; m < MR; ++m)
#pragma unroll
    for (int n = 0; n < NR; ++n)
#pragma unroll
      for (int i = 0; i < 4; ++i) {
        int r = row0 + wr * 64 + m * 16 + (lane >> 4) * 4 + i;
        int c = col0 + wc * 64 + n * 16 + (lane & 15);
        if (EPI == 0)
          ((u16*)Cp)[coff + (size_t)r * ldc + c] = f2bf(acc[m][n][i]);
        else if (EPI == 1)
          ((float*)Cp)[coff + (size_t)r * ldc + c] = acc[m][n][i] + bias[c];
        else
          ((u16*)Cp)[coff + (size_t)r * ldc + c] = f2bf(acc[m][n][i]);
      }
}

// ---------------------------------------------------------------- causal row softmax
// S = [32 bh][1024 q][1024 k] bf16. One wave per row; masks by column index.
// Rows q<512 touch only the first 512 columns (PV's VARK never reads beyond).
__global__ void __launch_bounds__(256) k_softmax(u16* __restrict__ S) {
  const int tid = threadIdx.x, lane = tid & 63, w = tid >> 6;
  const int row = blockIdx.x * 4 + w;
  const int q = row & 1023;
  u16* rowp = S + (size_t)(row >> 10) * 1048576 + (size_t)q * 1024;
  const int c0 = lane * 8, c1 = 512 + lane * 8;
  const bool hi = (q >= 512);
  s16x8 v0 = *(const s16x8*)(rowp + c0);
  s16x8 v1 = {};
  if (hi) v1 = *(const s16x8*)(rowp + c1);
  float f[16];
#pragma unroll
  for (int j = 0; j < 8; ++j) {
    f[j]     = (c0 + j <= q)       ? bf2f((u16)v0[j]) : -3e38f;
    f[8 + j] = (hi && c1 + j <= q) ? bf2f((u16)v1[j]) : -3e38f;
  }
  float m = f[0];
#pragma unroll
  for (int j = 1; j < 16; ++j) m = fmaxf(m, f[j]);
  m = fmaxf(m, __shfl_xor(m, 1));
  m = fmaxf(m, __shfl_xor(m, 2));
  m = fmaxf(m, __shfl_xor(m, 4));
  m = fmaxf(m, __shfl_xor(m, 8));
  m = fmaxf(m, __shfl_xor(m, 16));
  m = fmaxf(m, __shfl_xor(m, 32));
  float sum = 0.f;
#pragma unroll
  for (int j = 0; j < 16; ++j) { f[j] = __expf(f[j] - m); sum += f[j]; }
  sum += __shfl_xor(sum, 1);
  sum += __shfl_xor(sum, 2);
  sum += __shfl_xor(sum, 4);
  sum += __shfl_xor(sum, 8);
  sum += __shfl_xor(sum, 16);
  sum += __shfl_xor(sum, 32);
  const float inv = 1.f / sum;
#pragma unroll
  for (int j = 0; j < 8; ++j) {
    v0[j] = (short)f2bf(f[j] * inv);
    v1[j] = (short)f2bf(f[8 + j] * inv);
  }
  *(s16x8*)(rowp + c0) = v0;
  if (hi) *(s16x8*)(rowp + c1) = v1;
}

// ---------------------------------------------------------------- split-K=4 reduce (bf16 partials + bias -> f32)
// P = 4 x [4096][512] bf16 planes (stride 2M u16). Thread i: 8 consecutive
// outputs. grid 1024 x 256.
__global__ void k_reduce4(const u16* __restrict__ P, const float* __restrict__ bias,
                          float* __restrict__ out, int n8) {
  int i = blockIdx.x * 256 + threadIdx.x;
  if (i >= n8) return;
  const size_t e0 = (size_t)i * 8;
  const int cb = (int)(e0 & 511);
  float s[8];
#pragma unroll
  for (int j = 0; j < 8; ++j) s[j] = bias[cb + j];
#pragma unroll
  for (int p = 0; p < 4; ++p) {
    s16x8 v = *(const s16x8*)(P + (size_t)p * 2097152 + e0);
#pragma unroll
    for (int j = 0; j < 8; ++j) s[j] += bf2f((u16)v[j]);
  }
  float4 o0, o1;
  o0.x = s[0]; o0.y = s[1]; o0.z = s[2]; o0.w = s[3];
  o1.x = s[4]; o1.y = s[5]; o1.z = s[6]; o1.w = s[7];
  *(float4*)(out + e0) = o0;
  *(float4*)(out + e0 + 4) = o1;
}

// ---------------------------------------------------------------- launch
// Head-factored pipeline: G_h = Wq̂_h Wk_h^T, Wvo_h = Wv_h Wo_h fold the K/V
// projections:  y = x@G^T -> S = y@x^T (causal) -> softmax -> Z = P@x ->
// out = Z@WvoT^T + bo (split-K=4 bf16 partials + reduce).  8 launches total.
// G is stored H-INTERLEAVED [512][4096] (same C geometry as WvoT) so G and Wvo
// compute as ONE batched launch (zb selects the task via the batch strides).
// Workspace (u16 elems):
//   xb 0 | xT 2M | Wqb 4M | Wkb 6M | Wvb 8M | WoT 10M | G 12M | WvoT 14M
//   y 16M..32M | S 32M..64M (bf16 split-K partials alias S after Z) | Z 64M..80M
extern "C" void kernel_launch(void* const* d_in, const int* in_sizes, int n_in,
                              void* d_out, int out_size, void* d_ws, size_t ws_size,
                              hipStream_t stream) {
  (void)in_sizes; (void)n_in; (void)out_size; (void)ws_size;
  const float* x  = (const float*)d_in[0];
  const float* Wq = (const float*)d_in[1];
  const float* Wk = (const float*)d_in[2];
  const float* Wv = (const float*)d_in[3];
  const float* Wo = (const float*)d_in[4];
  const float* bo = (const float*)d_in[5];
  float* out = (float*)d_out;

  u16* ws   = (u16*)d_ws;
  u16* xb   = ws;                      // [4096][512]
  u16* xT   = ws + 2097152;            // [4][512][1024]
  u16* Wqb  = ws + 4194304;            // [512][4096] (scaled by 1/sqrt(512))
  u16* Wkb  = ws + 6291456;            // [512][4096]
  u16* Wvb  = ws + 8388608;            // [512][4096]
  u16* WoT  = ws + 10485760;           // [512][4096]
  u16* G    = ws + 12582912;           // [512][4096]  Gw[e'][h*512+e]
  u16* WvoT = ws + 14680064;           // [512][4096]
  u16* y    = ws + 16777216;           // [8][4096][512]
  u16* S    = ws + 33554432;           // [32][1024][1024]
  u16* Z    = ws + 67108864;           // [4096][4096]
  u16* Pp   = ws + 33554432;           // 4 x [4096][512] bf16 partials (alias S, dead after Z)

  const float qscale = 0.044194173824159216f;  // 1/sqrt(512)

  // ---- fused prologue (1 launch)
  k_prep<<<dim3(2048, 6), 256, 0, stream>>>(x, Wq, Wk, Wv, Wo, ws, qscale);

  // ---- G (zb=0) + Wvo (zb=1) as one batched launch, 128 blocks
  k_gemm2<0, 0, 0><<<dim3(4, 2, 16), 512, 0, stream>>>(
      Wkb, Wqb, (void*)G, nullptr, 512, 4096, 4096, 4096,
      4194304, 512, 4194304, 512, 2097152, 512);

  // ---- y_h = x @ G_h^T   [8][4096][512]   (B rows at ldb=4096, per-h offset 512)
  k_gemm2<0, 0, 0><<<dim3(4, 16, 8), 512, 0, stream>>>(
      xb, G, (void*)y, nullptr, 512, 512, 4096, 512,
      0, 0, 0, 512, 0, 2097152);

  // ---- S = y_h @ x_b^T  (causal 256-row strips), batched over 32 bh
  k_gemm2<0, 1, 0><<<dim3(8, 4, 32), 512, 0, stream>>>(
      y, xb, (void*)S, nullptr, 512, 512, 512, 1024,
      524288, 2097152, 524288, 0, 8388608, 1048576);

  // ---- causal softmax
  k_softmax<<<8192, 256, 0, stream>>>(S);

  // ---- Z = P @ x_b  (VARK heavy-first: 256-row strip by uses (by+1)*256 keys)
  k_gemm2<0, 0, 1><<<dim3(4, 4, 32), 512, 0, stream>>>(
      S, xT, (void*)Z, nullptr, 1024, 1024, 1024, 4096,
      8388608, 1048576, 524288, 0, 4194304, 512);

  // ---- out = Z @ WvoT^T + bo, split-K=4, bf16 partials (zh = k-chunk stride trick)
  k_gemm2<2, 0, 0><<<dim3(4, 16, 4), 512, 0, stream>>>(
      Z, WvoT, (void*)Pp, nullptr, 1024, 4096, 4096, 512,
      0, 1024, 0, 1024, 0, 2097152);
  k_reduce4<<<1024, 256, 0, stream>>>(Pp, bo, out, 262144);
}

// Round 17
// 168.981 us; speedup vs baseline: 1.1333x; 1.0116x over previous
//
#include <hip/hip_runtime.h>
#include <hip/hip_bf16.h>

typedef unsigned short u16;
typedef __attribute__((ext_vector_type(4))) float f32x4;
typedef __attribute__((ext_vector_type(8))) short s16x8;  // 8 x bf16 (4 VGPRs)
typedef __attribute__((ext_vector_type(4))) short s16x4;

#define DEVFN static __device__ __forceinline__

DEVFN u16 f2bf(float f) {  // fp32 -> bf16, round-nearest-even
  unsigned u = __float_as_uint(f);
  return (u16)((u + 0x7fffu + ((u >> 16) & 1u)) >> 16);
}
DEVFN float bf2f(u16 h) { return __uint_as_float(((unsigned)h) << 16); }

DEVFN void gl_lds16(const void* g, void* l) {  // async global->LDS, 16B/lane
  __builtin_amdgcn_global_load_lds(
      (const __attribute__((address_space(1))) unsigned int*)g,
      (__attribute__((address_space(3))) unsigned int*)l, 16, 0, 0);
}

DEVFN f32x4 mfma16(s16x8 a, s16x8 b, f32x4 c) {
  return __builtin_amdgcn_mfma_f32_16x16x32_bf16(a, b, c, 0, 0, 0);
}

// ---------------------------------------------------------------- fused prologue
// grid (2048, 5), 256 thr. Tasks by blockIdx.y:
//  0..2: cvt Wq/Wk/Wv f32 -> bf16 (Wq scaled by 1/sqrt(512))
//  3:    transpose Wo f32[4096][512] -> WoT bf16 [512][4096]     (512 blocks)
//  4:    x: ONE read -> BOTH xb bf16 [4096][512] (straight) and
//        xT bf16 [4][512][1024] (transposed)                      (512 blocks)
__global__ void k_prep(const float* __restrict__ x, const float* __restrict__ Wq,
                       const float* __restrict__ Wk, const float* __restrict__ Wv,
                       const float* __restrict__ Wo, u16* __restrict__ ws,
                       float qscale) {
  __shared__ float tile[64][65];
  const int z = blockIdx.y, bid = blockIdx.x, tid = threadIdx.x;
  if (z < 3) {
    const float4* src = (z == 0) ? (const float4*)Wq
                      : (z == 1) ? (const float4*)Wk : (const float4*)Wv;
    const float scale = (z == 0) ? qscale : 1.f;
    u16* d = ws + 4194304 + (size_t)z * 2097152;  // Wqb 4M / Wkb 6M / Wvb 8M
    int i = bid * 256 + tid;
    float4 v = src[i];
    s16x4 o;
    o[0] = (short)f2bf(v.x * scale); o[1] = (short)f2bf(v.y * scale);
    o[2] = (short)f2bf(v.z * scale); o[3] = (short)f2bf(v.w * scale);
    *(s16x4*)(d + (size_t)i * 4) = o;
    return;
  }
  if (bid >= 512) return;
  const int c = tid & 63, r4 = tid >> 6;
  if (z == 3) {  // Wo transpose: k0 x n0 tiles (K=4096, N=512)
    const int k0 = (bid & 63) * 64, n0 = (bid >> 6) * 64;
    u16* WoT = ws + 10485760;
#pragma unroll
    for (int i = 0; i < 16; ++i) {
      int r = i * 4 + r4;
      tile[r][c] = Wo[(size_t)(k0 + r) * 512 + n0 + c];
    }
    __syncthreads();
#pragma unroll
    for (int i = 0; i < 16; ++i) {
      int r = i * 4 + r4;
      WoT[(size_t)(n0 + r) * 4096 + k0 + c] = f2bf(tile[c][r]);
    }
  } else {  // x: cvt + transpose from one read. per-b 1024x512 -> 512x1024
    const int bz = bid >> 7, r0 = (bid & 15) * 64, c0 = ((bid >> 4) & 7) * 64;
    u16* xb = ws;
    u16* xT = ws + 2097152;
#pragma unroll
    for (int i = 0; i < 16; ++i) {  // load + straight bf16 copy (own elements)
      int r = i * 4 + r4;
      float v = x[(size_t)(bz * 1024 + r0 + r) * 512 + c0 + c];
      tile[r][c] = v;
      xb[(size_t)(bz * 1024 + r0 + r) * 512 + c0 + c] = f2bf(v);
    }
    __syncthreads();
#pragma unroll
    for (int i = 0; i < 16; ++i) {
      int r = i * 4 + r4;
      xT[(size_t)bz * 524288 + (size_t)(c0 + r) * 1024 + r0 + c] = f2bf(tile[c][r]);
    }
  }
}

// ---------------------------------------------------------------- batched GEMM: 256x128 tile, 8 waves
// r13-proven body: T1 XCD-chunked swizzle + T2 src/read chunk swizzle (0
// conflicts, r9) + T4 3-buffer counted-vmcnt pipeline, single-phase K-step.
// (6 intra-tile schedule variants tried r6-r14: all null or negative.)
// 8 waves = 4 row-groups x 2 col-groups; each wave owns 64x64 (16 MFMA/step).
// Batch via bz: offset += (bz>>3)*s?b + (bz&7)*s?h.
// EPI 0: C bf16;  1: C f32+bias;  2: C bf16 split-K partial.
// CAUSAL: skip when col0 >= row0+256.
// VARK: Klim = row0+256, by flipped (heavy strips dispatch first).
template <int EPI, int CAUSAL, int VARK>
__global__ void __launch_bounds__(512, 2) k_gemm2(
    const u16* __restrict__ A, const u16* __restrict__ Bt,
    void* __restrict__ Cp, const float* __restrict__ bias,
    int K, int lda, int ldb, int ldc,
    size_t sAb, size_t sAh, size_t sBb, size_t sBh, size_t sCb, size_t sCh) {
  constexpr int BM = 256, BN = 128, MR = 4, NR = 4;
  constexpr int LPT = 3;                          // 24 chunks / 8 waves
  constexpr int ABUF = BM * 32, BBUF = BN * 32;   // 8192 / 4096 u16
  // ---- T1 block-id swizzle
  const unsigned nx = gridDim.x, ny = gridDim.y;
  const unsigned nwg = nx * ny * gridDim.z;
  const unsigned L = blockIdx.x + nx * (blockIdx.y + ny * blockIdx.z);
  const unsigned o = (nwg & 7) ? L : ((L & 7) * (nwg >> 3) + (L >> 3));
  const unsigned bx = o % nx, o2 = o / nx;
  unsigned by = o2 % ny;
  const unsigned bz = o2 / ny;
  if (VARK) by = (ny - 1) - by;  // heavy-first dispatch order

  const int row0 = by * BM, col0 = bx * BN;
  if (CAUSAL && col0 >= row0 + BM) return;
  __shared__ alignas(16) u16 Alds[3 * ABUF];
  __shared__ alignas(16) u16 Blds[3 * BBUF];
  const int tid = threadIdx.x, lane = tid & 63, wv = tid >> 6;
  const int wr = wv >> 1, wc = wv & 1;             // 4 x 2 wave grid
  const int zb = bz >> 3, zh = bz & 7;
  const char* Ab = (const char*)(A + (size_t)zb * sAb + (size_t)zh * sAh);
  const char* Bb = (const char*)(Bt + (size_t)zb * sBb + (size_t)zh * sBh);
  const size_t coff = (size_t)zb * sCb + (size_t)zh * sCh;
  const int Klim = VARK ? (row0 + BM) : K;
  const int ntiles = Klim >> 5;
  const f32x4 zero4 = {0.f, 0.f, 0.f, 0.f};

  // staging: 24 x 1KB chunks (A:0..15, B:16..23), 3 per wave; source 16B-chunk
  // XOR-swizzled by rowlocal bits 1-2 ((lane>>3)&3) for a conflict-free read.
  const int scb = (((lane & 3) ^ ((lane >> 3) & 3))) * 16;
  auto stage = [&](int buf, int k0) {
    char* abase = (char*)(Alds + buf * ABUF);
    char* bbase = (char*)(Blds + buf * BBUF);
#pragma unroll
    for (int j = 0; j < 3; ++j) {
      int ch = wv * 3 + j;
      if (ch < 16) {
        int r = ch * 16 + (lane >> 2);
        gl_lds16(Ab + ((size_t)(row0 + r) * lda + k0) * 2 + scb, abase + ch * 1024);
      } else {
        int r = (ch - 16) * 16 + (lane >> 2);
        gl_lds16(Bb + ((size_t)(col0 + r) * ldb + k0) * 2 + scb,
                 bbase + (ch - 16) * 1024);
      }
    }
  };

  f32x4 acc[MR][NR];
#pragma unroll
  for (int m = 0; m < MR; ++m)
#pragma unroll
    for (int n = 0; n < NR; ++n) acc[m][n] = zero4;

  stage(0, 0);
  if (ntiles > 1) stage(1, 32);

  const int rcb = (((lane >> 4) ^ ((lane >> 1) & 3)) & 3) * 16;

  int t = 0;
  for (int k0 = 0; k0 < Klim; k0 += 32, ++t) {
    if (t + 1 < ntiles)
      asm volatile("s_waitcnt vmcnt(%0)" :: "i"(LPT) : "memory");
    else
      asm volatile("s_waitcnt vmcnt(0)" ::: "memory");
    __builtin_amdgcn_s_barrier();
    asm volatile("" ::: "memory");  // pin ds_reads below the barrier
    if (t + 2 < ntiles) stage((t + 2) % 3, k0 + 64);
    const char* abase = (const char*)(Alds + (t % 3) * ABUF);
    const char* bbase = (const char*)(Blds + (t % 3) * BBUF);
    s16x8 af[MR], bfr[NR];
#pragma unroll
    for (int m = 0; m < MR; ++m)
      af[m] = *(const s16x8*)(abase +
               (wr * 64 + m * 16 + (lane & 15)) * 64 + rcb);
#pragma unroll
    for (int n = 0; n < NR; ++n)
      bfr[n] = *(const s16x8*)(bbase +
                (wc * 64 + n * 16 + (lane & 15)) * 64 + rcb);
    __builtin_amdgcn_s_setprio(1);
#pragma unroll
    for (int m = 0; m < MR; ++m)
#pragma unroll
      for (int n = 0; n < NR; ++n) acc[m][n] = mfma16(af[m], bfr[n], acc[m][n]);
    __builtin_amdgcn_s_setprio(0);
  }
#pragma unroll
  for (int m = 0; m < MR; ++m)
#pragma unroll
    for (int n = 0; n < NR; ++n)
#pragma unroll
      for (int i = 0; i < 4; ++i) {
        int r = row0 + wr * 64 + m * 16 + (lane >> 4) * 4 + i;
        int c = col0 + wc * 64 + n * 16 + (lane & 15);
        if (EPI == 0)
          ((u16*)Cp)[coff + (size_t)r * ldc + c] = f2bf(acc[m][n][i]);
        else if (EPI == 1)
          ((float*)Cp)[coff + (size_t)r * ldc + c] = acc[m][n][i] + bias[c];
        else
          ((u16*)Cp)[coff + (size_t)r * ldc + c] = f2bf(acc[m][n][i]);
      }
}

// ---------------------------------------------------------------- causal row softmax
// S = [32 bh][1024 q][1024 k] bf16. One wave per row; masks by column index.
// r17 live-region guarding: LOADS only where cols <= q (masked lanes
// contribute -inf -> 0); STORES only where cols < E = ((q>>8)+1)*256 — the
// strip-end Z's VARK actually reads. Zeros in (q, E) are required and
// produced; cols >= E are never read by Z. Values stored where read are
// bit-identical to r16.
__global__ void __launch_bounds__(256) k_softmax(u16* __restrict__ S) {
  const int tid = threadIdx.x, lane = tid & 63, w = tid >> 6;
  const int row = blockIdx.x * 4 + w;
  const int q = row & 1023;
  const int E = ((q >> 8) + 1) << 8;  // 256/512/768/1024
  u16* rowp = S + (size_t)(row >> 10) * 1048576 + (size_t)q * 1024;
  const int c0 = lane * 8, c1 = 512 + lane * 8;
  const bool hi = (q >= 512);
  s16x8 v0 = {};
  if (c0 <= q) v0 = *(const s16x8*)(rowp + c0);
  s16x8 v1 = {};
  if (hi && c1 <= q) v1 = *(const s16x8*)(rowp + c1);
  float f[16];
#pragma unroll
  for (int j = 0; j < 8; ++j) {
    f[j]     = (c0 + j <= q)       ? bf2f((u16)v0[j]) : -3e38f;
    f[8 + j] = (hi && c1 + j <= q) ? bf2f((u16)v1[j]) : -3e38f;
  }
  float m = f[0];
#pragma unroll
  for (int j = 1; j < 16; ++j) m = fmaxf(m, f[j]);
  m = fmaxf(m, __shfl_xor(m, 1));
  m = fmaxf(m, __shfl_xor(m, 2));
  m = fmaxf(m, __shfl_xor(m, 4));
  m = fmaxf(m, __shfl_xor(m, 8));
  m = fmaxf(m, __shfl_xor(m, 16));
  m = fmaxf(m, __shfl_xor(m, 32));
  float sum = 0.f;
#pragma unroll
  for (int j = 0; j < 16; ++j) { f[j] = __expf(f[j] - m); sum += f[j]; }
  sum += __shfl_xor(sum, 1);
  sum += __shfl_xor(sum, 2);
  sum += __shfl_xor(sum, 4);
  sum += __shfl_xor(sum, 8);
  sum += __shfl_xor(sum, 16);
  sum += __shfl_xor(sum, 32);
  const float inv = 1.f / sum;
#pragma unroll
  for (int j = 0; j < 8; ++j) {
    v0[j] = (short)f2bf(f[j] * inv);
    v1[j] = (short)f2bf(f[8 + j] * inv);
  }
  if (c0 < E) *(s16x8*)(rowp + c0) = v0;
  if (hi && c1 < E) *(s16x8*)(rowp + c1) = v1;
}

// ---------------------------------------------------------------- split-K=4 reduce (bf16 partials + bias -> f32)
// P = 4 x [4096][512] bf16 planes (stride 2M u16). Thread i: 8 consecutive
// outputs. grid 1024 x 256.
__global__ void k_reduce4(const u16* __restrict__ P, const float* __restrict__ bias,
                          float* __restrict__ out, int n8) {
  int i = blockIdx.x * 256 + threadIdx.x;
  if (i >= n8) return;
  const size_t e0 = (size_t)i * 8;
  const int cb = (int)(e0 & 511);
  float s[8];
#pragma unroll
  for (int j = 0; j < 8; ++j) s[j] = bias[cb + j];
#pragma unroll
  for (int p = 0; p < 4; ++p) {
    s16x8 v = *(const s16x8*)(P + (size_t)p * 2097152 + e0);
#pragma unroll
    for (int j = 0; j < 8; ++j) s[j] += bf2f((u16)v[j]);
  }
  float4 o0, o1;
  o0.x = s[0]; o0.y = s[1]; o0.z = s[2]; o0.w = s[3];
  o1.x = s[4]; o1.y = s[5]; o1.z = s[6]; o1.w = s[7];
  *(float4*)(out + e0) = o0;
  *(float4*)(out + e0 + 4) = o1;
}

// ---------------------------------------------------------------- launch
// Head-factored pipeline: G_h = Wq̂_h Wk_h^T, Wvo_h = Wv_h Wo_h fold the K/V
// projections:  y = x@G^T -> S = y@x^T (causal) -> softmax -> Z = P@x ->
// out = Z@WvoT^T + bo (split-K=4 bf16 partials + reduce).  8 launches total.
// G is stored H-INTERLEAVED [512][4096] (same C geometry as WvoT) so G and Wvo
// compute as ONE batched launch (zb selects the task via the batch strides).
// Workspace (u16 elems):
//   xb 0 | xT 2M | Wqb 4M | Wkb 6M | Wvb 8M | WoT 10M | G 12M | WvoT 14M
//   y 16M..32M | S 32M..64M (bf16 split-K partials alias S after Z) | Z 64M..80M
extern "C" void kernel_launch(void* const* d_in, const int* in_sizes, int n_in,
                              void* d_out, int out_size, void* d_ws, size_t ws_size,
                              hipStream_t stream) {
  (void)in_sizes; (void)n_in; (void)out_size; (void)ws_size;
  const float* x  = (const float*)d_in[0];
  const float* Wq = (const float*)d_in[1];
  const float* Wk = (const float*)d_in[2];
  const float* Wv = (const float*)d_in[3];
  const float* Wo = (const float*)d_in[4];
  const float* bo = (const float*)d_in[5];
  float* out = (float*)d_out;

  u16* ws   = (u16*)d_ws;
  u16* xb   = ws;                      // [4096][512]
  u16* xT   = ws + 2097152;            // [4][512][1024]
  u16* Wqb  = ws + 4194304;            // [512][4096] (scaled by 1/sqrt(512))
  u16* Wkb  = ws + 6291456;            // [512][4096]
  u16* Wvb  = ws + 8388608;            // [512][4096]
  u16* WoT  = ws + 10485760;           // [512][4096]
  u16* G    = ws + 12582912;           // [512][4096]  Gw[e'][h*512+e]
  u16* WvoT = ws + 14680064;           // [512][4096]
  u16* y    = ws + 16777216;           // [8][4096][512]
  u16* S    = ws + 33554432;           // [32][1024][1024]
  u16* Z    = ws + 67108864;           // [4096][4096]
  u16* Pp   = ws + 33554432;           // 4 x [4096][512] bf16 partials (alias S, dead after Z)

  const float qscale = 0.044194173824159216f;  // 1/sqrt(512)

  // ---- fused prologue (1 launch; x read once for both xb and xT)
  k_prep<<<dim3(2048, 5), 256, 0, stream>>>(x, Wq, Wk, Wv, Wo, ws, qscale);

  // ---- G (zb=0) + Wvo (zb=1) as one batched launch, 128 blocks
  k_gemm2<0, 0, 0><<<dim3(4, 2, 16), 512, 0, stream>>>(
      Wkb, Wqb, (void*)G, nullptr, 512, 4096, 4096, 4096,
      4194304, 512, 4194304, 512, 2097152, 512);

  // ---- y_h = x @ G_h^T   [8][4096][512]   (B rows at ldb=4096, per-h offset 512)
  k_gemm2<0, 0, 0><<<dim3(4, 16, 8), 512, 0, stream>>>(
      xb, G, (void*)y, nullptr, 512, 512, 4096, 512,
      0, 0, 0, 512, 0, 2097152);

  // ---- S = y_h @ x_b^T  (causal 256-row strips), batched over 32 bh
  k_gemm2<0, 1, 0><<<dim3(8, 4, 32), 512, 0, stream>>>(
      y, xb, (void*)S, nullptr, 512, 512, 512, 1024,
      524288, 2097152, 524288, 0, 8388608, 1048576);

  // ---- causal softmax (live-region guarded)
  k_softmax<<<8192, 256, 0, stream>>>(S);

  // ---- Z = P @ x_b  (VARK heavy-first: 256-row strip by uses (by+1)*256 keys)
  k_gemm2<0, 0, 1><<<dim3(4, 4, 32), 512, 0, stream>>>(
      S, xT, (void*)Z, nullptr, 1024, 1024, 1024, 4096,
      8388608, 1048576, 524288, 0, 4194304, 512);

  // ---- out = Z @ WvoT^T + bo, split-K=4, bf16 partials (zh = k-chunk stride trick)
  k_gemm2<2, 0, 0><<<dim3(4, 16, 4), 512, 0, stream>>>(
      Z, WvoT, (void*)Pp, nullptr, 1024, 4096, 4096, 512,
      0, 1024, 0, 1024, 0, 2097152);
  k_reduce4<<<1024, 256, 0, stream>>>(Pp, bo, out, 262144);
}